// Round 1
// 669.551 us; speedup vs baseline: 1.5761x; 1.5761x over previous
//
#include <hip/hip_runtime.h>
#include <stdint.h>

typedef __bf16 b16x8 __attribute__((ext_vector_type(8)));
typedef float  f32x4 __attribute__((ext_vector_type(4)));
typedef unsigned short u16;
typedef unsigned int   u32;

// ---- ws layout (u16 elements): transposed bf16 weights ---------------------
#define W1T_P 0            // [512][1024]
#define W1T_T 524288       // [512][512]
#define W1T_M 786432
#define W2T_P 1048576      // [256][512]
#define W2T_T 1179648
#define W2T_M 1310720
// total ws: 1441792 u16 = 2.88 MB

// LDS staging tile: 64 rows x 256 bf16, stride 272 u16 (544 B):
//  - 544 = 34*16 -> every row 16B-aligned for ds_read_b128
//  - 544 B = 136 dwords = 8 mod 32 banks -> A-frag read pattern
//    (16 rows x 4 q-slots of 16B) spreads 8 dwords/bank: conflict-free
#define STG_STRIDE 272
#define STG_BUF    (64 * STG_STRIDE)   // 17408 u16 per buffer
#define H_STRIDE   520                 // u16; 1040 B rows, 16B-aligned

__device__ __forceinline__ u16 f2bf(float x) {  // round-to-nearest-even
    union { float f; u32 u; } v; v.f = x;
    u32 u = v.u;
    u += 0x7fffu + ((u >> 16) & 1u);
    return (u16)(u >> 16);
}
__device__ __forceinline__ f32x4 mfma16(b16x8 a, b16x8 b, f32x4 c) {
    return __builtin_amdgcn_mfma_f32_16x16x32_bf16(a, b, c, 0, 0, 0);
}
__device__ __forceinline__ b16x8 ld8(const u16* p) { return *(const b16x8*)p; }

__device__ __forceinline__ const float* tblFor(int type, int s,
        const float* agvT, const float* opT, const float* machT) {
    if (s == 0) return agvT;
    if (type != 0) return machT;          // trans/move: seg>=1 is machine
    return (s == 3) ? machT : opT;        // pick: 1,2 = op, 3 = machine
}

// ---------------- weight transpose: fp32 src[R][C] -> bf16 dst[C][R] --------
__global__ void transpose_all(const float* __restrict__ pw1, const float* __restrict__ tw1,
                              const float* __restrict__ mw1, const float* __restrict__ pw2,
                              const float* __restrict__ tw2, const float* __restrict__ mw2,
                              u16* __restrict__ wsE)
{
    const int mat = blockIdx.y;
    const float* src; u16* dst; int R, C;
    switch (mat) {
        case 0: src = pw1; R = 1024; C = 512; dst = wsE + W1T_P; break;
        case 1: src = tw1; R = 512;  C = 512; dst = wsE + W1T_T; break;
        case 2: src = mw1; R = 512;  C = 512; dst = wsE + W1T_M; break;
        case 3: src = pw2; R = 512;  C = 256; dst = wsE + W2T_P; break;
        case 4: src = tw2; R = 512;  C = 256; dst = wsE + W2T_T; break;
        default: src = mw2; R = 512; C = 256; dst = wsE + W2T_M; break;
    }
    const int tilesC = C >> 5, tilesR = R >> 5;
    const int bx = blockIdx.x % tilesC, by = blockIdx.x / tilesC;
    if (by >= tilesR) return;
    __shared__ u16 tile[32][33];
    const int tx = threadIdx.x & 31, ty = threadIdx.x >> 5;   // 256 threads
    #pragma unroll
    for (int i = 0; i < 4; ++i)
        tile[ty + i * 8][tx] = f2bf(src[(by * 32 + ty + i * 8) * C + bx * 32 + tx]);
    __syncthreads();
    #pragma unroll
    for (int i = 0; i < 4; ++i)
        dst[(bx * 32 + ty + i * 8) * R + by * 32 + tx] = tile[tx][ty + i * 8];
}

// ---------------- wait rows: broadcast fp32 wait_emb ------------------------
__global__ void wait_fill(const float* __restrict__ wait_emb, float* __restrict__ out, int n)
{
    int i = blockIdx.x * 256 + threadIdx.x;
    if (i < n) out[i] = wait_emb[i & 255];
}

// ---------------- fused gather + MLP (pick / trans / move by blockIdx.y) ----
// block: 1024 threads (16 waves) x 64 rows.
// Layer 1: gathered X rows are staged ONCE per block into LDS (bf16,
// conflict-free padded tile), double-buffered across 256-wide K segments with
// a T14 issue-early/write-late split so HBM/L3 gather latency hides under the
// MFMA phase. Each wave owns a 32-col N-slice (acc1 = 32 f32/lane -> fits
// the 128-reg/4-waves-per-EU budget WITH staging registers).
__global__ __launch_bounds__(1024, 4)
void mlp_kernel(const u16* __restrict__ wsE,
                const float* __restrict__ opTab, const float* __restrict__ machTab,
                const float* __restrict__ agvTab,
                const float* __restrict__ p_b1, const float* __restrict__ p_b2,
                const float* __restrict__ t_b1, const float* __restrict__ t_b2,
                const float* __restrict__ m_b1, const float* __restrict__ m_b2,
                const int* __restrict__ p_agv, const int* __restrict__ p_from,
                const int* __restrict__ p_to,  const int* __restrict__ p_mach,
                const int* __restrict__ t_agv, const int* __restrict__ t_mach,
                const int* __restrict__ m_agv, const int* __restrict__ m_mach,
                float* __restrict__ out,
                int n_wait, int rowsPerType, int nOp, int nMach, int nAgv)
{
    __shared__ __align__(16) u16 sStg[2 * STG_BUF];    // 69632 B (X double-buffer)
    __shared__ __align__(16) u16 sH[64 * H_STRIDE];    // 66560 B (hidden acts)
    __shared__ int sIdx[256];

    const int type = blockIdx.y;
    const int row0 = blockIdx.x * 64;
    const int tid  = threadIdx.x;
    const int lane = tid & 63;
    const int wv   = tid >> 6;     // wave 0..15
    const int l15  = lane & 15;
    const int q    = lane >> 4;    // quad 0..3
    const int srow = tid >> 4;     // staging: row 0..63
    const int sc   = tid & 15;     // staging: col-group 0..15 (16 floats each)

    int nseg;
    const u16 *w1t, *w2t;
    const float *b1, *b2;
    const int *i0, *i1, *i2, *i3;
    int outRowBase;
    if (type == 0) {
        nseg = 4;  w1t = wsE + W1T_P; w2t = wsE + W2T_P;
        b1 = p_b1; b2 = p_b2;
        i0 = p_agv; i1 = p_from; i2 = p_to; i3 = p_mach;
        outRowBase = n_wait;
    } else if (type == 1) {
        nseg = 2;  w1t = wsE + W1T_T; w2t = wsE + W2T_T;
        b1 = t_b1; b2 = t_b2;
        i0 = t_agv; i1 = t_mach; i2 = t_agv; i3 = t_mach;
        outRowBase = n_wait + rowsPerType;
    } else {
        nseg = 2;  w1t = wsE + W1T_M; w2t = wsE + W2T_M;
        b1 = m_b1; b2 = m_b2;
        i0 = m_agv; i1 = m_mach; i2 = m_agv; i3 = m_mach;
        outRowBase = n_wait + 2 * rowsPerType;
    }
    const int K1 = nseg << 8;

    // gather indices for this row block (clamped)
    if (tid < (nseg << 6)) {
        int seg = tid >> 6, r = tid & 63;
        const int* ip = (seg == 0) ? i0 : (seg == 1) ? i1 : (seg == 2) ? i2 : i3;
        int lim = (seg == 0) ? nAgv
                 : (type == 0) ? ((seg == 3) ? nMach : nOp) : nMach;
        int rr = row0 + r;
        if (rr >= rowsPerType) rr = rowsPerType - 1;
        int v = ip[rr];
        if (v < 0) v = 0;
        if (v >= lim) v = lim - 1;
        sIdx[tid] = v;
    }
    __syncthreads();

    // ---------------- layer 1: H = leaky(X @ W1 + b1) ----------------
    int aAddr[4];
    #pragma unroll
    for (int t = 0; t < 4; ++t)
        aAddr[t] = (t * 16 + l15) * STG_STRIDE + q * 8;
    const int wOff0 = (wv * 32 + l15) * K1 + q * 8;    // W1t[n][k], u = 0
    const int wOff1 = wOff0 + 16 * K1;                 // u = 1

    f32x4 acc1[4][2];
    #pragma unroll
    for (int t = 0; t < 4; ++t) {
        acc1[t][0] = (f32x4)0.f;
        acc1[t][1] = (f32x4)0.f;
    }

    // prologue: stage seg 0 into buffer 0
    {
        const float* tb = tblFor(type, 0, agvTab, opTab, machTab);
        const float* src = tb + sIdx[srow] * 256 + sc * 8;
        f32x4 pre0 = *(const f32x4*)(src);
        f32x4 pre1 = *(const f32x4*)(src + 4);
        f32x4 pre2 = *(const f32x4*)(src + 128);
        f32x4 pre3 = *(const f32x4*)(src + 132);
        u16* dst = sStg + srow * STG_STRIDE + sc * 8;
        b16x8 a;
        a[0]=(__bf16)pre0[0]; a[1]=(__bf16)pre0[1]; a[2]=(__bf16)pre0[2]; a[3]=(__bf16)pre0[3];
        a[4]=(__bf16)pre1[0]; a[5]=(__bf16)pre1[1]; a[6]=(__bf16)pre1[2]; a[7]=(__bf16)pre1[3];
        *(b16x8*)(dst) = a;
        a[0]=(__bf16)pre2[0]; a[1]=(__bf16)pre2[1]; a[2]=(__bf16)pre2[2]; a[3]=(__bf16)pre2[3];
        a[4]=(__bf16)pre3[0]; a[5]=(__bf16)pre3[1]; a[6]=(__bf16)pre3[2]; a[7]=(__bf16)pre3[3];
        *(b16x8*)(dst + 128) = a;
    }
    __syncthreads();

    int bufo = 0;
    for (int sg = 0; sg < nseg; ++sg) {
        const u16* sA = sStg + bufo * STG_BUF;
        const u16* wb = w1t + sg * 256;
        const bool hasNext = (sg + 1) < nseg;

        // T14 issue-early: next segment's gather loads go out BEFORE compute
        f32x4 pre0, pre1, pre2, pre3;
        if (hasNext) {
            const float* tb = tblFor(type, sg + 1, agvTab, opTab, machTab);
            const float* src = tb + sIdx[((sg + 1) << 6) + srow] * 256 + sc * 8;
            pre0 = *(const f32x4*)(src);
            pre1 = *(const f32x4*)(src + 4);
            pre2 = *(const f32x4*)(src + 128);
            pre3 = *(const f32x4*)(src + 132);
        }

        // first half of compute (64 MFMAs) hides the gather latency
        #pragma unroll
        for (int s8 = 0; s8 < 4; ++s8) {
            b16x8 aF[4];
            #pragma unroll
            for (int t = 0; t < 4; ++t)
                aF[t] = *(const b16x8*)&sA[aAddr[t] + s8 * 32];
            b16x8 bF0 = ld8(wb + wOff0 + s8 * 32);
            b16x8 bF1 = ld8(wb + wOff1 + s8 * 32);
            #pragma unroll
            for (int t = 0; t < 4; ++t) {
                acc1[t][0] = mfma16(aF[t], bF0, acc1[t][0]);
                acc1[t][1] = mfma16(aF[t], bF1, acc1[t][1]);
            }
        }

        // write-late: convert + LDS write into the other buffer
        if (hasNext) {
            u16* dst = sStg + (bufo ^ 1) * STG_BUF + srow * STG_STRIDE + sc * 8;
            b16x8 a;
            a[0]=(__bf16)pre0[0]; a[1]=(__bf16)pre0[1]; a[2]=(__bf16)pre0[2]; a[3]=(__bf16)pre0[3];
            a[4]=(__bf16)pre1[0]; a[5]=(__bf16)pre1[1]; a[6]=(__bf16)pre1[2]; a[7]=(__bf16)pre1[3];
            *(b16x8*)(dst) = a;
            a[0]=(__bf16)pre2[0]; a[1]=(__bf16)pre2[1]; a[2]=(__bf16)pre2[2]; a[3]=(__bf16)pre2[3];
            a[4]=(__bf16)pre3[0]; a[5]=(__bf16)pre3[1]; a[6]=(__bf16)pre3[2]; a[7]=(__bf16)pre3[3];
            *(b16x8*)(dst + 128) = a;
        }

        // second half of compute
        #pragma unroll
        for (int s8 = 4; s8 < 8; ++s8) {
            b16x8 aF[4];
            #pragma unroll
            for (int t = 0; t < 4; ++t)
                aF[t] = *(const b16x8*)&sA[aAddr[t] + s8 * 32];
            b16x8 bF0 = ld8(wb + wOff0 + s8 * 32);
            b16x8 bF1 = ld8(wb + wOff1 + s8 * 32);
            #pragma unroll
            for (int t = 0; t < 4; ++t) {
                acc1[t][0] = mfma16(aF[t], bF0, acc1[t][0]);
                acc1[t][1] = mfma16(aF[t], bF1, acc1[t][1]);
            }
        }

        __syncthreads();
        bufo ^= 1;
    }

    // epilogue 1: bias + leaky + bf16 -> padded LDS H
    #pragma unroll
    for (int u = 0; u < 2; ++u) {
        int c = wv * 32 + u * 16 + l15;
        float bb = b1[c];
        #pragma unroll
        for (int t = 0; t < 4; ++t) {
            #pragma unroll
            for (int r = 0; r < 4; ++r) {
                float x = acc1[t][u][r] + bb;
                x = x > 0.f ? x : 0.01f * x;
                int row = t * 16 + q * 4 + r;       // C/D: row = quad*4 + reg
                sH[row * H_STRIDE + c] = f2bf(x);
            }
        }
    }
    __syncthreads();

    // ---------------- layer 2: out = H @ W2 + b2 ----------------
    const int w2Off = (wv * 16 + l15) * 512 + q * 8;   // W2t[n][k], 16 cols/wave

    f32x4 acc2[4];
    #pragma unroll
    for (int t = 0; t < 4; ++t) acc2[t] = (f32x4)0.f;

    #pragma unroll
    for (int s2 = 0; s2 < 16; ++s2) {
        b16x8 bF = ld8(w2t + w2Off + s2 * 32);
        #pragma unroll
        for (int t = 0; t < 4; ++t) {
            b16x8 hF = *(const b16x8*)&sH[(t * 16 + l15) * H_STRIDE + s2 * 32 + q * 8];
            acc2[t] = mfma16(hF, bF, acc2[t]);
        }
    }

    // epilogue 2: bias -> fp32 global (non-temporal: out is write-once,
    // keep the gather tables resident in L2/L3 instead)
    const int obase = (outRowBase + row0) * 256;
    {
        int c = wv * 16 + l15;
        float bb = b2[c];
        #pragma unroll
        for (int t = 0; t < 4; ++t) {
            #pragma unroll
            for (int r = 0; r < 4; ++r) {
                int row = t * 16 + q * 4 + r;
                if (row0 + row < rowsPerType)
                    __builtin_nontemporal_store(acc2[t][r] + bb,
                                                &out[obase + row * 256 + c]);
            }
        }
    }
}

extern "C" void kernel_launch(void* const* d_in, const int* in_sizes, int n_in,
                              void* d_out, int out_size, void* d_ws, size_t ws_size,
                              hipStream_t stream)
{
    const float* op_emb   = (const float*)d_in[0];
    const float* mach_emb = (const float*)d_in[1];
    const float* agv_emb  = (const float*)d_in[2];
    const float* wait_emb = (const float*)d_in[3];
    const float* pick_w1  = (const float*)d_in[4];
    const float* pick_b1  = (const float*)d_in[5];
    const float* pick_w2  = (const float*)d_in[6];
    const float* pick_b2  = (const float*)d_in[7];
    const float* trans_w1 = (const float*)d_in[8];
    const float* trans_b1 = (const float*)d_in[9];
    const float* trans_w2 = (const float*)d_in[10];
    const float* trans_b2 = (const float*)d_in[11];
    const float* move_w1  = (const float*)d_in[12];
    const float* move_b1  = (const float*)d_in[13];
    const float* move_w2  = (const float*)d_in[14];
    const float* move_b2  = (const float*)d_in[15];
    const int* pick_agv   = (const int*)d_in[16];
    const int* pick_from  = (const int*)d_in[17];
    const int* pick_to    = (const int*)d_in[18];
    const int* pick_mach  = (const int*)d_in[19];
    const int* trans_agv  = (const int*)d_in[20];
    const int* trans_mach = (const int*)d_in[21];
    const int* move_agv   = (const int*)d_in[22];
    const int* move_mach  = (const int*)d_in[23];

    const int P = in_sizes[16];
    const int T = in_sizes[20];
    const int M = in_sizes[22];
    const int n_wait = out_size / 256 - P - T - M;
    const int nOp   = in_sizes[0] / 256;
    const int nMach = in_sizes[1] / 256;
    const int nAgv  = in_sizes[2] / 256;

    u16* wsE = (u16*)d_ws;
    float* out = (float*)d_out;

    transpose_all<<<dim3(512, 6), 256, 0, stream>>>(pick_w1, trans_w1, move_w1,
                                                    pick_w2, trans_w2, move_w2, wsE);
    if (n_wait > 0)
        wait_fill<<<(n_wait * 256 + 255) / 256, 256, 0, stream>>>(
            wait_emb, out, n_wait * 256);

    mlp_kernel<<<dim3((P + 63) / 64, 3), 1024, 0, stream>>>(
        wsE,
        op_emb, mach_emb, agv_emb,
        pick_b1, pick_b2, trans_b1, trans_b2, move_b1, move_b2,
        pick_agv, pick_from, pick_to, pick_mach,
        trans_agv, trans_mach, move_agv, move_mach,
        out, n_wait, P, nOp, nMach, nAgv);
}

// Round 2
// 666.155 us; speedup vs baseline: 1.5841x; 1.0051x over previous
//
#include <hip/hip_runtime.h>
#include <stdint.h>

typedef __bf16 b16x8 __attribute__((ext_vector_type(8)));
typedef float  f32x4 __attribute__((ext_vector_type(4)));
typedef unsigned short u16;
typedef unsigned int   u32;

// ---- ws layout (u16 elements): transposed bf16 weights ---------------------
#define W1T_P 0            // [512][1024]
#define W1T_T 524288       // [512][512]
#define W1T_M 786432
#define W2T_P 1048576      // [256][512]
#define W2T_T 1179648
#define W2T_M 1310720
// total ws: 1441792 u16 = 2.88 MB

// X staging tile: 64 rows x 256 bf16, stride 264 u16 (528 B):
//  - 528 = 33*16 -> rows 16B-aligned for ds_read_b128
//  - 528 B = 132 dwords = 4 mod 32 banks -> row r starts at bank 4r mod 32:
//    8 distinct b128 start-banks, 8 lanes each = uniform (minimum) for b128
#define STG_STRIDE 264
// hidden tile: 64 rows x 512 bf16, stride 520 u16 (1040 B = 260 dw = 4 mod 32)
#define H_STRIDE   520
// sStg (16896 u16) and sH (33280 u16) are timeline-disjoint -> ALIASED.
#define SMEM_U16   (64 * H_STRIDE)   // 33280 u16 = 66560 B

__device__ __forceinline__ u16 f2bf(float x) {  // round-to-nearest-even
    union { float f; u32 u; } v; v.f = x;
    u32 u = v.u;
    u += 0x7fffu + ((u >> 16) & 1u);
    return (u16)(u >> 16);
}
__device__ __forceinline__ f32x4 mfma16(b16x8 a, b16x8 b, f32x4 c) {
    return __builtin_amdgcn_mfma_f32_16x16x32_bf16(a, b, c, 0, 0, 0);
}
__device__ __forceinline__ b16x8 ld8(const u16* p) { return *(const b16x8*)p; }

__device__ __forceinline__ const float* tblFor(int type, int s,
        const float* agvT, const float* opT, const float* machT) {
    if (s == 0) return agvT;
    if (type != 0) return machT;          // trans/move: seg>=1 is machine
    return (s == 3) ? machT : opT;        // pick: 1,2 = op, 3 = machine
}

// ---------------- weight transpose: fp32 src[R][C] -> bf16 dst[C][R] --------
__global__ void transpose_all(const float* __restrict__ pw1, const float* __restrict__ tw1,
                              const float* __restrict__ mw1, const float* __restrict__ pw2,
                              const float* __restrict__ tw2, const float* __restrict__ mw2,
                              u16* __restrict__ wsE)
{
    const int mat = blockIdx.y;
    const float* src; u16* dst; int R, C;
    switch (mat) {
        case 0: src = pw1; R = 1024; C = 512; dst = wsE + W1T_P; break;
        case 1: src = tw1; R = 512;  C = 512; dst = wsE + W1T_T; break;
        case 2: src = mw1; R = 512;  C = 512; dst = wsE + W1T_M; break;
        case 3: src = pw2; R = 512;  C = 256; dst = wsE + W2T_P; break;
        case 4: src = tw2; R = 512;  C = 256; dst = wsE + W2T_T; break;
        default: src = mw2; R = 512; C = 256; dst = wsE + W2T_M; break;
    }
    const int tilesC = C >> 5, tilesR = R >> 5;
    const int bx = blockIdx.x % tilesC, by = blockIdx.x / tilesC;
    if (by >= tilesR) return;
    __shared__ u16 tile[32][33];
    const int tx = threadIdx.x & 31, ty = threadIdx.x >> 5;   // 256 threads
    #pragma unroll
    for (int i = 0; i < 4; ++i)
        tile[ty + i * 8][tx] = f2bf(src[(by * 32 + ty + i * 8) * C + bx * 32 + tx]);
    __syncthreads();
    #pragma unroll
    for (int i = 0; i < 4; ++i)
        dst[(bx * 32 + ty + i * 8) * R + by * 32 + tx] = tile[tx][ty + i * 8];
}

// ---------------- wait rows: broadcast fp32 wait_emb ------------------------
__global__ void wait_fill(const float* __restrict__ wait_emb, float* __restrict__ out, int n)
{
    int i = blockIdx.x * 256 + threadIdx.x;
    if (i < n) out[i] = wait_emb[i & 255];
}

// ---------------- fused gather + MLP (pick / trans / move by blockIdx.y) ----
// block: 512 threads (8 waves) x 64 rows, 2 blocks/CU (LDS 67584 B, 128 regs).
// Layer 1: X staged once per block into LDS (single buffer, barrier-fenced);
// inter-block TLP (2 resident blocks) hides the per-seg gather latency.
// 8 waves each own a 64-col N-slice: A-LDS redundancy 8x (vs 16x at 16 waves).
// sH aliases the staging buffer (timeline-disjoint) to stay under 80 KB.
__global__ __launch_bounds__(512, 4)
void mlp_kernel(const u16* __restrict__ wsE,
                const float* __restrict__ opTab, const float* __restrict__ machTab,
                const float* __restrict__ agvTab,
                const float* __restrict__ p_b1, const float* __restrict__ p_b2,
                const float* __restrict__ t_b1, const float* __restrict__ t_b2,
                const float* __restrict__ m_b1, const float* __restrict__ m_b2,
                const int* __restrict__ p_agv, const int* __restrict__ p_from,
                const int* __restrict__ p_to,  const int* __restrict__ p_mach,
                const int* __restrict__ t_agv, const int* __restrict__ t_mach,
                const int* __restrict__ m_agv, const int* __restrict__ m_mach,
                float* __restrict__ out,
                int n_wait, int rowsPerType, int nOp, int nMach, int nAgv)
{
    __shared__ __align__(16) u16 sMem[SMEM_U16];   // 66560 B, dual-purpose
    __shared__ int sIdx[256];
    u16* const sStg = sMem;                        // layer-1 X staging
    u16* const sH   = sMem;                        // layer-2 hidden acts

    const int type = blockIdx.y;
    const int row0 = blockIdx.x * 64;
    const int tid  = threadIdx.x;
    const int lane = tid & 63;
    const int wv   = tid >> 6;     // wave 0..7
    const int l15  = lane & 15;
    const int q    = lane >> 4;    // quad 0..3
    const int srow = tid >> 3;     // staging: row 0..63 (8 threads/row)
    const int sc8  = tid & 7;      // staging: 32-float col group

    int nseg;
    const u16 *w1t, *w2t;
    const float *b1, *b2;
    const int *i0, *i1, *i2, *i3;
    int outRowBase;
    if (type == 0) {
        nseg = 4;  w1t = wsE + W1T_P; w2t = wsE + W2T_P;
        b1 = p_b1; b2 = p_b2;
        i0 = p_agv; i1 = p_from; i2 = p_to; i3 = p_mach;
        outRowBase = n_wait;
    } else if (type == 1) {
        nseg = 2;  w1t = wsE + W1T_T; w2t = wsE + W2T_T;
        b1 = t_b1; b2 = t_b2;
        i0 = t_agv; i1 = t_mach; i2 = t_agv; i3 = t_mach;
        outRowBase = n_wait + rowsPerType;
    } else {
        nseg = 2;  w1t = wsE + W1T_M; w2t = wsE + W2T_M;
        b1 = m_b1; b2 = m_b2;
        i0 = m_agv; i1 = m_mach; i2 = m_agv; i3 = m_mach;
        outRowBase = n_wait + 2 * rowsPerType;
    }
    const int K1 = nseg << 8;

    // gather indices for this row block (clamped)
    if (tid < (nseg << 6)) {
        int seg = tid >> 6, r = tid & 63;
        const int* ip = (seg == 0) ? i0 : (seg == 1) ? i1 : (seg == 2) ? i2 : i3;
        int lim = (seg == 0) ? nAgv
                 : (type == 0) ? ((seg == 3) ? nMach : nOp) : nMach;
        int rr = row0 + r;
        if (rr >= rowsPerType) rr = rowsPerType - 1;
        int v = ip[rr];
        if (v < 0) v = 0;
        if (v >= lim) v = lim - 1;
        sIdx[tid] = v;
    }
    __syncthreads();

    // ---------------- layer 1: H = leaky(X @ W1 + b1) ----------------
    int aAddr[4];
    #pragma unroll
    for (int t = 0; t < 4; ++t)
        aAddr[t] = (t * 16 + l15) * STG_STRIDE + q * 8;
    int wOff[4];
    #pragma unroll
    for (int u = 0; u < 4; ++u)
        wOff[u] = (wv * 64 + u * 16 + l15) * K1 + q * 8;    // W1t[n][k]

    f32x4 acc1[4][4];
    #pragma unroll
    for (int t = 0; t < 4; ++t)
        #pragma unroll
        for (int u = 0; u < 4; ++u)
            acc1[t][u] = (f32x4)0.f;

    for (int sg = 0; sg < nseg; ++sg) {
        if (sg) __syncthreads();           // prior-seg A reads done before overwrite
        // stage this seg: each thread gathers 32 floats of one row, cvt->bf16
        {
            const float* src = tblFor(type, sg, agvTab, opTab, machTab)
                             + sIdx[(sg << 6) + srow] * 256 + sc8 * 32;
            f32x4 g[8];
            #pragma unroll
            for (int j = 0; j < 8; ++j)
                g[j] = *(const f32x4*)(src + j * 4);
            u16* dst = sStg + srow * STG_STRIDE + sc8 * 32;
            #pragma unroll
            for (int j = 0; j < 4; ++j) {
                b16x8 a;
                a[0] = (__bf16)g[2*j][0]; a[1] = (__bf16)g[2*j][1];
                a[2] = (__bf16)g[2*j][2]; a[3] = (__bf16)g[2*j][3];
                a[4] = (__bf16)g[2*j+1][0]; a[5] = (__bf16)g[2*j+1][1];
                a[6] = (__bf16)g[2*j+1][2]; a[7] = (__bf16)g[2*j+1][3];
                *(b16x8*)(dst + j * 8) = a;
            }
        }
        __syncthreads();

        const u16* wb = w1t + sg * 256;
        #pragma unroll
        for (int s8 = 0; s8 < 8; ++s8) {
            b16x8 aF[4], bF[4];
            #pragma unroll
            for (int t = 0; t < 4; ++t)
                aF[t] = *(const b16x8*)&sStg[aAddr[t] + s8 * 32];
            #pragma unroll
            for (int u = 0; u < 4; ++u)
                bF[u] = ld8(wb + wOff[u] + s8 * 32);
            #pragma unroll
            for (int t = 0; t < 4; ++t)
                #pragma unroll
                for (int u = 0; u < 4; ++u)
                    acc1[t][u] = mfma16(aF[t], bF[u], acc1[t][u]);
        }
    }
    __syncthreads();   // last-seg sStg reads done before sH (aliased) writes

    // epilogue 1: bias + leaky + bf16 -> padded LDS H
    #pragma unroll
    for (int u = 0; u < 4; ++u) {
        int c = wv * 64 + u * 16 + l15;
        float bb = b1[c];
        #pragma unroll
        for (int t = 0; t < 4; ++t) {
            #pragma unroll
            for (int r = 0; r < 4; ++r) {
                float x = acc1[t][u][r] + bb;
                x = x > 0.f ? x : 0.01f * x;
                int row = t * 16 + q * 4 + r;       // C/D: row = quad*4 + reg
                sH[row * H_STRIDE + c] = f2bf(x);
            }
        }
    }
    __syncthreads();

    // ---------------- layer 2: out = H @ W2 + b2 ----------------
    int w2Off[2];
    #pragma unroll
    for (int u = 0; u < 2; ++u)
        w2Off[u] = (wv * 32 + u * 16 + l15) * 512 + q * 8;  // W2t[n][k]

    f32x4 acc2[4][2];
    #pragma unroll
    for (int t = 0; t < 4; ++t)
        #pragma unroll
        for (int u = 0; u < 2; ++u)
            acc2[t][u] = (f32x4)0.f;

    #pragma unroll
    for (int s2 = 0; s2 < 16; ++s2) {
        b16x8 hF[4], bF[2];
        #pragma unroll
        for (int t = 0; t < 4; ++t)
            hF[t] = *(const b16x8*)&sH[(t * 16 + l15) * H_STRIDE + s2 * 32 + q * 8];
        #pragma unroll
        for (int u = 0; u < 2; ++u)
            bF[u] = ld8(w2t + w2Off[u] + s2 * 32);
        #pragma unroll
        for (int t = 0; t < 4; ++t)
            #pragma unroll
            for (int u = 0; u < 2; ++u)
                acc2[t][u] = mfma16(hF[t], bF[u], acc2[t][u]);
    }

    // epilogue 2: bias -> fp32 global (non-temporal: out is write-once)
    const int obase = (outRowBase + row0) * 256;
    #pragma unroll
    for (int u = 0; u < 2; ++u) {
        int c = wv * 32 + u * 16 + l15;
        float bb = b2[c];
        #pragma unroll
        for (int t = 0; t < 4; ++t) {
            #pragma unroll
            for (int r = 0; r < 4; ++r) {
                int row = t * 16 + q * 4 + r;
                if (row0 + row < rowsPerType)
                    __builtin_nontemporal_store(acc2[t][u][r] + bb,
                                                &out[obase + row * 256 + c]);
            }
        }
    }
}

extern "C" void kernel_launch(void* const* d_in, const int* in_sizes, int n_in,
                              void* d_out, int out_size, void* d_ws, size_t ws_size,
                              hipStream_t stream)
{
    const float* op_emb   = (const float*)d_in[0];
    const float* mach_emb = (const float*)d_in[1];
    const float* agv_emb  = (const float*)d_in[2];
    const float* wait_emb = (const float*)d_in[3];
    const float* pick_w1  = (const float*)d_in[4];
    const float* pick_b1  = (const float*)d_in[5];
    const float* pick_w2  = (const float*)d_in[6];
    const float* pick_b2  = (const float*)d_in[7];
    const float* trans_w1 = (const float*)d_in[8];
    const float* trans_b1 = (const float*)d_in[9];
    const float* trans_w2 = (const float*)d_in[10];
    const float* trans_b2 = (const float*)d_in[11];
    const float* move_w1  = (const float*)d_in[12];
    const float* move_b1  = (const float*)d_in[13];
    const float* move_w2  = (const float*)d_in[14];
    const float* move_b2  = (const float*)d_in[15];
    const int* pick_agv   = (const int*)d_in[16];
    const int* pick_from  = (const int*)d_in[17];
    const int* pick_to    = (const int*)d_in[18];
    const int* pick_mach  = (const int*)d_in[19];
    const int* trans_agv  = (const int*)d_in[20];
    const int* trans_mach = (const int*)d_in[21];
    const int* move_agv   = (const int*)d_in[22];
    const int* move_mach  = (const int*)d_in[23];

    const int P = in_sizes[16];
    const int T = in_sizes[20];
    const int M = in_sizes[22];
    const int n_wait = out_size / 256 - P - T - M;
    const int nOp   = in_sizes[0] / 256;
    const int nMach = in_sizes[1] / 256;
    const int nAgv  = in_sizes[2] / 256;

    u16* wsE = (u16*)d_ws;
    float* out = (float*)d_out;

    transpose_all<<<dim3(512, 6), 256, 0, stream>>>(pick_w1, trans_w1, move_w1,
                                                    pick_w2, trans_w2, move_w2, wsE);
    if (n_wait > 0)
        wait_fill<<<(n_wait * 256 + 255) / 256, 256, 0, stream>>>(
            wait_emb, out, n_wait * 256);

    mlp_kernel<<<dim3((P + 63) / 64, 3), 512, 0, stream>>>(
        wsE,
        op_emb, mach_emb, agv_emb,
        pick_b1, pick_b2, trans_b1, trans_b2, move_b1, move_b2,
        pick_agv, pick_from, pick_to, pick_mach,
        trans_agv, trans_mach, move_agv, move_mach,
        out, n_wait, P, nOp, nMach, nAgv);
}